// Round 13
// baseline (50.054 us; speedup 1.0000x reference)
//
#include <hip/hip_runtime.h>
#include <math.h>

#define BATCH 8192
#define DIM   128
#define E1    256
#define E2    128
#define BRF   16     // fused: batch rows per block; grid 512 -> 2 blocks/CU -> 4 waves/SIMD

// PROBE ROUND: fused_kernel launched 4x (idempotent) -> Delta = 3 x fused_dur.
#define FUSED_REPEATS 4

// output float offsets (x_hat, adj, mu, lv concatenated)
#define OUT_XHAT 0
#define OUT_ADJ  (BATCH*DIM)                 // 1048576
#define OUT_MU   (OUT_ADJ + DIM*DIM)         // 1064960
#define OUT_LV   (OUT_MU + BATCH*DIM)        // 2113536

// workspace BYTE offsets (frag-linear bf16 weight images + small f32 blocks)
#define W1F   0u          // 32768 bf16 = 65536 B
#define W2F   65536u      // 32768 bf16
#define WMUF  131072u     // 16384 bf16 = 32768 B
#define WLVF  163840u     // 16384 bf16
#define AHF   196608u     // 16384 bf16
#define COEF  229376u     // f32[8]: a1,a3,a5,s_safe
#define VBUF  229408u     // f32[96]: v[32], bg1[32], w2[32]

typedef __attribute__((ext_vector_type(8))) short s8v;   // 8 bf16 (4 VGPR)
typedef __attribute__((ext_vector_type(4))) float f4v;   // MFMA accumulator
#define MFMA(a, b, c) __builtin_amdgcn_mfma_f32_16x16x32_bf16(a, b, c, 0, 0, 0)

__device__ __forceinline__ ushort f2bf(float f) {        // RNE f32 -> bf16
    uint u = __float_as_uint(f);
    u += 0x7fffu + ((u >> 16) & 1u);
    return (ushort)(u >> 16);
}

// fast sigmoid + self-loop + threshold; single source for adj/degrees/ahat.
__device__ __forceinline__ float sigm_fast(float l, int i, int j, int it) {
    float gv = 1.0f / (1.0f + __expf(-l));
    if (i == j) gv = 1.0f;
    if (it > 50 && gv < 0.1f) gv = 0.0f;
    return gv;
}

// ---------------------------------------------------------------------------
// Kernel 1 (prep): blocks 0-23 convert weights f32 -> fragment-linear bf16.
// Block 24: adjacency, a_hat frags, tanh-poly coefficients (fast __expf).
// ---------------------------------------------------------------------------
__global__ __launch_bounds__(512) void prep_kernel(
    const float* __restrict__ W1,  const float* __restrict__ W2,
    const float* __restrict__ Wmu, const float* __restrict__ Wlv,
    const float* __restrict__ logits, const float* __restrict__ Wf,
    const float* __restrict__ Wg1, const float* __restrict__ bg1,
    const float* __restrict__ Wg2, const int* __restrict__ itp,
    float* __restrict__ out, char* __restrict__ wsb)
{
    __shared__ float gsm[16384];
    __shared__ float aux[768];
    __shared__ float vsh[32];
    const int t = threadIdx.x;

    if (blockIdx.x < 24) {
        const int tid = (int)blockIdx.x * 512 + t;       // 0..12287
        const float* W; ushort* dst; int e, N_, ksLog;
        if (tid < 4096)       { W = W1;  dst = (ushort*)(wsb + W1F);  e = tid * 8;           N_ = 256; ksLog = 2; }
        else if (tid < 8192)  { W = W2;  dst = (ushort*)(wsb + W2F);  e = (tid - 4096) * 8;  N_ = 128; ksLog = 3; }
        else if (tid < 10240) { W = Wmu; dst = (ushort*)(wsb + WMUF); e = (tid - 8192) * 8;  N_ = 128; ksLog = 2; }
        else                  { W = Wlv; dst = (ushort*)(wsb + WLVF); e = (tid - 10240) * 8; N_ = 128; ksLog = 2; }
        const int frag = e >> 9, l = (e >> 3) & 63;
        const int nt = frag >> ksLog, ks = frag & ((1 << ksLog) - 1);
        const int k0 = ks * 32 + ((l >> 4) << 3);
        const int n  = (nt << 4) + (l & 15);
        uint pk[4];
        #pragma unroll
        for (int jj = 0; jj < 4; ++jj) {
            ushort lo = f2bf(W[(k0 + 2 * jj) * N_ + n]);
            ushort hi = f2bf(W[(k0 + 2 * jj + 1) * N_ + n]);
            pk[jj] = (uint)lo | ((uint)hi << 16);
        }
        *(uint4*)(dst + e) = make_uint4(pk[0], pk[1], pk[2], pk[3]);
        return;
    }

    // ---------------- graph block (fast sigmoid throughout) ----------------
    const int it = itp[0];
    {
        const int j = t & 127, rq = t >> 7;
        float dp = 0.0f;
        #pragma unroll 4
        for (int i = rq * 32; i < rq * 32 + 32; ++i) {
            float gv = sigm_fast(logits[i * DIM + j], i, j, it);
            gsm[i * DIM + j] = gv;
            if (gv > 0.0f) dp += 1.0f;
        }
        aux[rq * 128 + j] = dp;                    // partial col sums (d_in)
    }
    __syncthreads();
    if (t < 128) {
        float d = aux[t] + aux[128 + t] + aux[256 + t] + aux[384 + t];
        aux[512 + t] = 1.0f / sqrtf(fmaxf(d, 1.0f));      // rin[j]
    }
    __syncthreads();
    {
        const int i = t & 127, cq = t >> 7;
        float dp = 0.0f;
        #pragma unroll 4
        for (int c = cq * 32; c < cq * 32 + 32; ++c)
            if (gsm[i * DIM + c] > 0.0f) dp += 1.0f;
        aux[cq * 128 + i] = dp;                    // partial row sums (d_out)
    }
    __syncthreads();
    if (t < 128) {
        float d = aux[t] + aux[128 + t] + aux[256 + t] + aux[384 + t];
        aux[640 + t] = 1.0f / sqrtf(fmaxf(d, 1.0f));      // rdout[i]
    }
    __syncthreads();
    #pragma unroll 4
    for (int p = 0; p < 32; ++p) {                 // adj out + ahat in place
        int idx = t + 512 * p;
        int i = idx >> 7, j = idx & 127;
        float gv = gsm[idx];
        out[OUT_ADJ + idx] = gv;
        gsm[idx] = gv * aux[640 + i] * aux[512 + j];
    }
    if (t < 32) {                                  // v = W_feat @ W_g1
        float acc = 0.0f;
        for (int k = 0; k < 64; ++k) acc = fmaf(Wf[k], Wg1[k * 32 + t], acc);
        vsh[t] = acc;
        float* vb = (float*)(wsb + VBUF);
        vb[t] = acc; vb[32 + t] = bg1[t]; vb[64 + t] = Wg2[t];
    }
    __syncthreads();
    {                                              // ahat fragments (K=N=128)
        ushort* ahf = (ushort*)(wsb + AHF);
        #pragma unroll
        for (int c = 0; c < 4; ++c) {
            int e = (t + c * 512) * 8;
            int frag = e >> 9, l = (e >> 3) & 63;
            int nt = frag >> 2, ks = frag & 3;
            int k0 = ks * 32 + ((l >> 4) << 3);
            int n  = (nt << 4) + (l & 15);
            uint pk[4];
            #pragma unroll
            for (int jj = 0; jj < 4; ++jj) {
                ushort lo = f2bf(gsm[(k0 + 2 * jj) * DIM + n]);
                ushort hi = f2bf(gsm[(k0 + 2 * jj + 1) * DIM + n]);
                pk[jj] = (uint)lo | ((uint)hi << 16);
            }
            *(uint4*)(ahf + e) = make_uint4(pk[0], pk[1], pk[2], pk[3]);
        }
    }
    if (t == 0) {                                  // tanh poly coefficients
        float a1 = 0, a3 = 0, a5 = 0, vmax = 0, bmax = 0;
        for (int c = 0; c < 32; ++c) {
            float v = vsh[c], w = Wg2[c], v2 = v * v;
            a1 += w * v;
            a3 -= w * v * v2 * (1.0f / 3.0f);
            a5 += w * v * v2 * v2 * (2.0f / 15.0f);
            vmax = fmaxf(vmax, fabsf(v));
            bmax = fmaxf(bmax, fabsf(bg1[c]));
        }
        float* cf = (float*)(wsb + COEF);
        cf[0] = a1; cf[1] = a3; cf[2] = a5;
        cf[3] = (bmax == 0.0f) ? 0.2f / fmaxf(vmax, 1e-30f) : -1.0f;
    }
}

// ---------------------------------------------------------------------------
// Kernel 2 (fused): 16 batch rows/block, 512 threads = 8 waves, grid 512.
// IDEMPOTENT: reads x/eps/ws, writes out; z lives only in LDS.
// ---------------------------------------------------------------------------
__global__ __launch_bounds__(512, 4) void fused_kernel(
    const float* __restrict__ x,   const float* __restrict__ eps,
    const float* __restrict__ b1,  const float* __restrict__ b2,
    const float* __restrict__ bmu, const float* __restrict__ blv,
    const float* __restrict__ bg2p,
    float* __restrict__ out, char* __restrict__ wsb)
{
    __shared__ __attribute__((aligned(16))) ushort bufA[2048]; // x frags, then z frags
    __shared__ __attribute__((aligned(16))) ushort bufB[4096]; // h1 frags, then t frags
    __shared__ __attribute__((aligned(16))) ushort bufC[2048]; // h2 frags
    __shared__ float vls[96];

    const int t = threadIdx.x;
    const int lane = t & 63, wid = t >> 6;          // 8 waves
    const int fr = lane & 15, fq = lane >> 4;       // C/D: col=fr, rows=fq*4+q
    const int row0 = (int)blockIdx.x * BRF;

    // ---- eps prefetch in C-fragment order ----
    float epr[4];
    {
        const float* eb = eps + (size_t)(row0 + fq * 4) * DIM + wid * 16 + fr;
        #pragma unroll
        for (int q = 0; q < 4; ++q) epr[q] = eb[q * DIM];
    }

    if (t < 96) vls[t] = ((const float*)(wsb + VBUF))[t];

    // ---- stage x tile (16 rows) -> bf16 A-fragments; 4 floats/thread ----
    {
        const int r = t & 15, c16 = t >> 4;          // c16: 4-float column group
        const int k0 = c16 * 4;
        const int ks = k0 >> 5, g = (k0 & 31) >> 3, h = (k0 >> 2) & 1;
        float4 u = *(const float4*)(x + (size_t)(row0 + r) * DIM + k0);
        uint p0 = (uint)f2bf(u.x) | ((uint)f2bf(u.y) << 16);
        uint p1 = (uint)f2bf(u.z) | ((uint)f2bf(u.w) << 16);
        *(uint2*)&bufA[(ks * 64 + g * 16 + r) * 8 + h * 4] = make_uint2(p0, p1);
    }

    // ---- prefetch ALL layer-1 B fragments before the barrier (32 VGPR) ----
    const ushort* w1f = (const ushort*)(wsb + W1F);
    s8v w1r[2][4];
    #pragma unroll
    for (int n = 0; n < 2; ++n)
        #pragma unroll
        for (int ks = 0; ks < 4; ++ks)
            w1r[n][ks] = *(const s8v*)&w1f[(((2 * wid + n) * 4 + ks) * 64 + lane) * 8];
    __syncthreads();

    // ---- layer 1: h1 = relu(x@W1+b1), N=256; wave w -> cols [w*32,+32) ----
    {
        f4v acc[2] = {{0,0,0,0},{0,0,0,0}};
        #pragma unroll
        for (int ks = 0; ks < 4; ++ks) {
            s8v a = *(const s8v*)&bufA[(ks * 64 + lane) * 8];
            #pragma unroll
            for (int n = 0; n < 2; ++n)
                acc[n] = MFMA(a, w1r[n][ks], acc[n]);
        }
        __syncthreads();            // x-frag reads done (bufA reused for z)
        #pragma unroll
        for (int n = 0; n < 2; ++n) {
            int col = (2 * wid + n) * 16 + fr;       // k-index for layer 2
            float bb = b1[col];
            int base = (col >> 5) * 512 + (((col >> 3) & 3) * 16) * 8 + (col & 7);
            #pragma unroll
            for (int q = 0; q < 4; ++q)
                bufB[base + (fq * 4 + q) * 8] = f2bf(fmaxf(acc[n][q] + bb, 0.0f));
        }
    }
    __syncthreads();

    // ---- layer 2: h2 = relu(h1@W2+b2), K=256, N=128; wave -> cols [w*16,+16) ----
    {
        const ushort* w2f = (const ushort*)(wsb + W2F);
        f4v acc = {0, 0, 0, 0};
        #pragma unroll
        for (int ks = 0; ks < 8; ++ks) {
            s8v a = *(const s8v*)&bufB[(ks * 64 + lane) * 8];
            s8v b = *(const s8v*)&w2f[((wid * 8 + ks) * 64 + lane) * 8];
            acc = MFMA(a, b, acc);
        }
        int col = wid * 16 + fr;
        float bb = b2[col];
        int base = (col >> 5) * 512 + (((col >> 3) & 3) * 16) * 8 + (col & 7);
        #pragma unroll
        for (int q = 0; q < 4; ++q)
            bufC[base + (fq * 4 + q) * 8] = f2bf(fmaxf(acc[q] + bb, 0.0f));
    }
    __syncthreads();

    // ---- mu / lv + z (z frags restaged into bufA) ----
    {
        const ushort* wmf = (const ushort*)(wsb + WMUF);
        const ushort* wlf = (const ushort*)(wsb + WLVF);
        f4v am = {0, 0, 0, 0}, al = {0, 0, 0, 0};
        #pragma unroll
        for (int ks = 0; ks < 4; ++ks) {
            s8v a = *(const s8v*)&bufC[(ks * 64 + lane) * 8];
            int fi = ((wid * 4 + ks) * 64 + lane) * 8;
            s8v bm = *(const s8v*)&wmf[fi];
            s8v bl = *(const s8v*)&wlf[fi];
            am = MFMA(a, bm, am);
            al = MFMA(a, bl, al);
        }
        int col = wid * 16 + fr;
        float bm = bmu[col], bl = blv[col];
        int base = (col >> 5) * 512 + (((col >> 3) & 3) * 16) * 8 + (col & 7);
        #pragma unroll
        for (int q = 0; q < 4; ++q) {
            int grow = row0 + fq * 4 + q;
            float mu = am[q] + bm;
            float lv = al[q] + bl;
            out[OUT_MU + grow * DIM + col] = mu;
            out[OUT_LV + grow * DIM + col] = lv;
            float z = fmaf(epr[q], __expf(0.5f * lv), mu);
            bufA[base + (fq * 4 + q) * 8] = f2bf(z);   // z frags into bufA
        }
    }
    __syncthreads();

    // ---- decoder: s = z@ahat ; t = P(s) ; xhat = t@ahat + bg2 ----
    const ushort* ahf = (const ushort*)(wsb + AHF);
    const float* cf = (const float*)(wsb + COEF);
    const float a1 = cf[0], a3 = cf[1], a5 = cf[2], ssafe = cf[3];
    const int acol = wid * 16 + fr;

    s8v bfr[4];                                     // ahat n-tile wid (16 VGPR)
    #pragma unroll
    for (int ks = 0; ks < 4; ++ks)
        bfr[ks] = *(const s8v*)&ahf[((wid * 4 + ks) * 64 + lane) * 8];

    f4v sa = {0, 0, 0, 0};
    #pragma unroll
    for (int ks = 0; ks < 4; ++ks) {
        s8v a = *(const s8v*)&bufA[(ks * 64 + lane) * 8];
        sa = MFMA(a, bfr[ks], sa);
    }
    __syncthreads();                 // bufB free (layer-2 reads long done)

    {
        int base = (acol >> 5) * 512 + (((acol >> 3) & 3) * 16) * 8 + (acol & 7);
        #pragma unroll
        for (int q = 0; q < 4; ++q) {
            float s = sa[q];
            float tv;
            if (fabsf(s) < ssafe) {                 // poly path (always, in practice)
                float s2 = s * s;
                tv = s * fmaf(s2, fmaf(s2, a5, a3), a1);
            } else {                                // exact fallback
                tv = 0.0f;
                for (int c = 0; c < 32; ++c)
                    tv = fmaf(vls[64 + c], tanhf(fmaf(s, vls[c], vls[32 + c])), tv);
            }
            bufB[base + (fq * 4 + q) * 8] = f2bf(tv);
        }
    }
    __syncthreads();

    f4v xa = {0, 0, 0, 0};
    #pragma unroll
    for (int ks = 0; ks < 4; ++ks) {
        s8v a = *(const s8v*)&bufB[(ks * 64 + lane) * 8];
        xa = MFMA(a, bfr[ks], xa);
    }
    const float bg2v = bg2p[0];
    #pragma unroll
    for (int q = 0; q < 4; ++q)
        out[OUT_XHAT + (size_t)(row0 + fq * 4 + q) * DIM + acol] = xa[q] + bg2v;
}

// ---------------------------------------------------------------------------
extern "C" void kernel_launch(void* const* d_in, const int* in_sizes, int n_in,
                              void* d_out, int out_size, void* d_ws, size_t ws_size,
                              hipStream_t stream)
{
    const float* x      = (const float*)d_in[0];
    const float* eps    = (const float*)d_in[1];
    const float* W1     = (const float*)d_in[2];
    const float* b1     = (const float*)d_in[3];
    const float* W2     = (const float*)d_in[4];
    const float* b2     = (const float*)d_in[5];
    const float* Wmu    = (const float*)d_in[6];
    const float* bmu    = (const float*)d_in[7];
    const float* Wlv    = (const float*)d_in[8];
    const float* blv    = (const float*)d_in[9];
    const float* logits = (const float*)d_in[10];
    const float* Wf     = (const float*)d_in[11];
    const float* Wg1    = (const float*)d_in[12];
    const float* bg1    = (const float*)d_in[13];
    const float* Wg2    = (const float*)d_in[14];
    const float* bg2    = (const float*)d_in[15];
    const int*   itp    = (const int*)d_in[16];
    float* out = (float*)d_out;
    char* wsb  = (char*)d_ws;

    hipLaunchKernelGGL(prep_kernel, dim3(25), dim3(512), 0, stream,
                       W1, W2, Wmu, Wlv, logits, Wf, Wg1, bg1, Wg2, itp, out, wsb);
    // PROBE: fused is idempotent; extra launches measure its true duration:
    // dur(this round) - dur(round 12) = (FUSED_REPEATS-1) x fused_dur.
    for (int r = 0; r < FUSED_REPEATS; ++r)
        hipLaunchKernelGGL(fused_kernel, dim3(BATCH / BRF), dim3(512), 0, stream,
                           x, eps, b1, b2, bmu, blv, bg2, out, wsb);
}

// Round 14
// 27.739 us; speedup vs baseline: 1.8045x; 1.8045x over previous
//
#include <hip/hip_runtime.h>
#include <math.h>

#define BATCH 8192
#define DIM   128
#define E1    256
#define E2    128
#define BRF   32     // fused: rows/block; grid 256, (512,4) -> 2 blocks/CU -> 16 waves/CU

// output float offsets (x_hat, adj, mu, lv concatenated)
#define OUT_XHAT 0
#define OUT_ADJ  (BATCH*DIM)                 // 1048576
#define OUT_MU   (OUT_ADJ + DIM*DIM)         // 1064960
#define OUT_LV   (OUT_MU + BATCH*DIM)        // 2113536

// workspace BYTE offsets (frag-linear bf16 weight images + small f32 blocks)
#define W1F   0u          // 32768 bf16 = 65536 B
#define W2F   65536u      // 32768 bf16
#define WMUF  131072u     // 16384 bf16 = 32768 B
#define WLVF  163840u     // 16384 bf16
#define AHF   196608u     // 16384 bf16
#define COEF  229376u     // f32[8]: a1,a3,a5,s_safe
#define VBUF  229408u     // f32[96]: v[32], bg1[32], w2[32]

typedef __attribute__((ext_vector_type(8))) short s8v;   // 8 bf16 (4 VGPR)
typedef __attribute__((ext_vector_type(4))) float f4v;   // MFMA accumulator
#define MFMA(a, b, c) __builtin_amdgcn_mfma_f32_16x16x32_bf16(a, b, c, 0, 0, 0)

__device__ __forceinline__ ushort f2bf(float f) {        // RNE f32 -> bf16
    uint u = __float_as_uint(f);
    u += 0x7fffu + ((u >> 16) & 1u);
    return (ushort)(u >> 16);
}

// fast sigmoid + self-loop + threshold; single source for adj/degrees/ahat.
__device__ __forceinline__ float sigm_fast(float l, int i, int j, int it) {
    float gv = 1.0f / (1.0f + __expf(-l));
    if (i == j) gv = 1.0f;
    if (it > 50 && gv < 0.1f) gv = 0.0f;
    return gv;
}

// ---------------------------------------------------------------------------
// Kernel 1 (prep): blocks 0-23 convert weights f32 -> fragment-linear bf16.
// Block 24: adjacency, a_hat frags, tanh-poly coefficients (fast __expf).
// Fragment-linear layout for a K x N matrix: frag (nt, ks) holds the 16x32
// tile cols [nt*16,+16) x rows [ks*32,+32); elem ((nt*nKs+ks)*64 + l)*8 + j
// stores W[ks*32 + (l>>4)*8 + j][nt*16 + (l&15)].
// ---------------------------------------------------------------------------
__global__ __launch_bounds__(512) void prep_kernel(
    const float* __restrict__ W1,  const float* __restrict__ W2,
    const float* __restrict__ Wmu, const float* __restrict__ Wlv,
    const float* __restrict__ logits, const float* __restrict__ Wf,
    const float* __restrict__ Wg1, const float* __restrict__ bg1,
    const float* __restrict__ Wg2, const int* __restrict__ itp,
    float* __restrict__ out, char* __restrict__ wsb)
{
    __shared__ float gsm[16384];
    __shared__ float aux[768];
    __shared__ float vsh[32];
    const int t = threadIdx.x;

    if (blockIdx.x < 24) {
        const int tid = (int)blockIdx.x * 512 + t;       // 0..12287
        const float* W; ushort* dst; int e, N_, ksLog;
        if (tid < 4096)       { W = W1;  dst = (ushort*)(wsb + W1F);  e = tid * 8;           N_ = 256; ksLog = 2; }
        else if (tid < 8192)  { W = W2;  dst = (ushort*)(wsb + W2F);  e = (tid - 4096) * 8;  N_ = 128; ksLog = 3; }
        else if (tid < 10240) { W = Wmu; dst = (ushort*)(wsb + WMUF); e = (tid - 8192) * 8;  N_ = 128; ksLog = 2; }
        else                  { W = Wlv; dst = (ushort*)(wsb + WLVF); e = (tid - 10240) * 8; N_ = 128; ksLog = 2; }
        const int frag = e >> 9, l = (e >> 3) & 63;
        const int nt = frag >> ksLog, ks = frag & ((1 << ksLog) - 1);
        const int k0 = ks * 32 + ((l >> 4) << 3);
        const int n  = (nt << 4) + (l & 15);
        uint pk[4];
        #pragma unroll
        for (int jj = 0; jj < 4; ++jj) {
            ushort lo = f2bf(W[(k0 + 2 * jj) * N_ + n]);
            ushort hi = f2bf(W[(k0 + 2 * jj + 1) * N_ + n]);
            pk[jj] = (uint)lo | ((uint)hi << 16);
        }
        *(uint4*)(dst + e) = make_uint4(pk[0], pk[1], pk[2], pk[3]);
        return;
    }

    // ---------------- graph block (fast sigmoid throughout) ----------------
    const int it = itp[0];
    {
        const int j = t & 127, rq = t >> 7;
        float dp = 0.0f;
        #pragma unroll 4
        for (int i = rq * 32; i < rq * 32 + 32; ++i) {
            float gv = sigm_fast(logits[i * DIM + j], i, j, it);
            gsm[i * DIM + j] = gv;
            if (gv > 0.0f) dp += 1.0f;
        }
        aux[rq * 128 + j] = dp;                    // partial col sums (d_in)
    }
    __syncthreads();
    if (t < 128) {
        float d = aux[t] + aux[128 + t] + aux[256 + t] + aux[384 + t];
        aux[512 + t] = 1.0f / sqrtf(fmaxf(d, 1.0f));      // rin[j]
    }
    __syncthreads();
    {
        const int i = t & 127, cq = t >> 7;
        float dp = 0.0f;
        #pragma unroll 4
        for (int c = cq * 32; c < cq * 32 + 32; ++c)
            if (gsm[i * DIM + c] > 0.0f) dp += 1.0f;
        aux[cq * 128 + i] = dp;                    // partial row sums (d_out)
    }
    __syncthreads();
    if (t < 128) {
        float d = aux[t] + aux[128 + t] + aux[256 + t] + aux[384 + t];
        aux[640 + t] = 1.0f / sqrtf(fmaxf(d, 1.0f));      // rdout[i]
    }
    __syncthreads();
    #pragma unroll 4
    for (int p = 0; p < 32; ++p) {                 // adj out + ahat in place
        int idx = t + 512 * p;
        int i = idx >> 7, j = idx & 127;
        float gv = gsm[idx];
        out[OUT_ADJ + idx] = gv;
        gsm[idx] = gv * aux[640 + i] * aux[512 + j];
    }
    if (t < 32) {                                  // v = W_feat @ W_g1
        float acc = 0.0f;
        for (int k = 0; k < 64; ++k) acc = fmaf(Wf[k], Wg1[k * 32 + t], acc);
        vsh[t] = acc;
        float* vb = (float*)(wsb + VBUF);
        vb[t] = acc; vb[32 + t] = bg1[t]; vb[64 + t] = Wg2[t];
    }
    __syncthreads();
    {                                              // ahat fragments (K=N=128)
        ushort* ahf = (ushort*)(wsb + AHF);
        #pragma unroll
        for (int c = 0; c < 4; ++c) {
            int e = (t + c * 512) * 8;
            int frag = e >> 9, l = (e >> 3) & 63;
            int nt = frag >> 2, ks = frag & 3;
            int k0 = ks * 32 + ((l >> 4) << 3);
            int n  = (nt << 4) + (l & 15);
            uint pk[4];
            #pragma unroll
            for (int jj = 0; jj < 4; ++jj) {
                ushort lo = f2bf(gsm[(k0 + 2 * jj) * DIM + n]);
                ushort hi = f2bf(gsm[(k0 + 2 * jj + 1) * DIM + n]);
                pk[jj] = (uint)lo | ((uint)hi << 16);
            }
            *(uint4*)(ahf + e) = make_uint4(pk[0], pk[1], pk[2], pk[3]);
        }
    }
    if (t == 0) {                                  // tanh poly coefficients
        float a1 = 0, a3 = 0, a5 = 0, vmax = 0, bmax = 0;
        for (int c = 0; c < 32; ++c) {
            float v = vsh[c], w = Wg2[c], v2 = v * v;
            a1 += w * v;
            a3 -= w * v * v2 * (1.0f / 3.0f);
            a5 += w * v * v2 * v2 * (2.0f / 15.0f);
            vmax = fmaxf(vmax, fabsf(v));
            bmax = fmaxf(bmax, fabsf(bg1[c]));
        }
        float* cf = (float*)(wsb + COEF);
        cf[0] = a1; cf[1] = a3; cf[2] = a5;
        cf[3] = (bmax == 0.0f) ? 0.2f / fmaxf(vmax, 1e-30f) : -1.0f;
    }
}

// ---------------------------------------------------------------------------
// Kernel 2 (fused): 32 batch rows/block (2 m-tiles), 512 threads = 8 waves.
// Grid 256; __launch_bounds__(512,4) -> 2 blocks/CU = 16 waves/CU (VGPR cap
// 128) COMBINED with halved L2 weight traffic (each B-frag reused for both
// m-tiles in registers). Round 9 geometry at round 11 occupancy.
// ---------------------------------------------------------------------------
__global__ __launch_bounds__(512, 4) void fused_kernel(
    const float* __restrict__ x,   const float* __restrict__ eps,
    const float* __restrict__ b1,  const float* __restrict__ b2,
    const float* __restrict__ bmu, const float* __restrict__ blv,
    const float* __restrict__ bg2p,
    float* __restrict__ out, char* __restrict__ wsb)
{
    __shared__ __attribute__((aligned(16))) ushort bufA[4096]; // x/z frags [mt][4][64][8]
    __shared__ __attribute__((aligned(16))) ushort bufB[8192]; // h1 frags [mt][8][64][8]; t reuse
    __shared__ __attribute__((aligned(16))) ushort bufC[4096]; // h2 frags [mt][4][64][8]
    __shared__ float vls[96];

    const int t = threadIdx.x;
    const int lane = t & 63, wid = t >> 6;          // 8 waves
    const int fr = lane & 15, fq = lane >> 4;       // C/D: col=fr, rows=fq*4+q
    const int row0 = (int)blockIdx.x * BRF;

    // ---- eps prefetch in C-fragment order ----
    float epr[2][4];
    {
        const float* eb = eps + (size_t)(row0 + fq * 4) * DIM + wid * 16 + fr;
        #pragma unroll
        for (int mt = 0; mt < 2; ++mt)
            #pragma unroll
            for (int q = 0; q < 4; ++q)
                epr[mt][q] = eb[(mt * 16 + q) * DIM];
    }

    if (t < 96) vls[t] = ((const float*)(wsb + VBUF))[t];

    // ---- stage x tile (32 rows) -> bf16 A-fragments ----
    {
        const int r = t & 31, g = (t >> 5) & 3, ks = t >> 7;
        const float* src = x + (size_t)(row0 + r) * DIM + ks * 32 + g * 8;
        float4 u0 = *(const float4*)src;
        float4 u1 = *(const float4*)(src + 4);
        uint p0 = (uint)f2bf(u0.x) | ((uint)f2bf(u0.y) << 16);
        uint p1 = (uint)f2bf(u0.z) | ((uint)f2bf(u0.w) << 16);
        uint p2 = (uint)f2bf(u1.x) | ((uint)f2bf(u1.y) << 16);
        uint p3 = (uint)f2bf(u1.z) | ((uint)f2bf(u1.w) << 16);
        *(uint4*)&bufA[(((r >> 4) * 4 + ks) * 64 + g * 16 + (r & 15)) * 8] =
            make_uint4(p0, p1, p2, p3);
    }
    __syncthreads();

    // ---- layer 1: h1 = relu(x@W1+b1), N=256; wave w -> cols [w*32,+32) ----
    {
        const ushort* w1f = (const ushort*)(wsb + W1F);
        f4v acc[2][2] = {{{0,0,0,0},{0,0,0,0}},{{0,0,0,0},{0,0,0,0}}};  // [mt][n]
        #pragma unroll
        for (int ks = 0; ks < 4; ++ks) {
            s8v a0 = *(const s8v*)&bufA[((0 * 4 + ks) * 64 + lane) * 8];
            s8v a1 = *(const s8v*)&bufA[((1 * 4 + ks) * 64 + lane) * 8];
            #pragma unroll
            for (int n = 0; n < 2; ++n) {
                s8v b = *(const s8v*)&w1f[(((2 * wid + n) * 4 + ks) * 64 + lane) * 8];
                acc[0][n] = MFMA(a0, b, acc[0][n]);
                acc[1][n] = MFMA(a1, b, acc[1][n]);
            }
        }
        #pragma unroll
        for (int n = 0; n < 2; ++n) {
            int col = (2 * wid + n) * 16 + fr;      // k-index for layer 2
            float bb = b1[col];
            #pragma unroll
            for (int mt = 0; mt < 2; ++mt) {
                int base = ((mt * 8 + (col >> 5)) * 64 + ((col >> 3) & 3) * 16) * 8 + (col & 7);
                #pragma unroll
                for (int q = 0; q < 4; ++q)
                    bufB[base + (fq * 4 + q) * 8] = f2bf(fmaxf(acc[mt][n][q] + bb, 0.0f));
            }
        }
    }
    __syncthreads();

    // ---- layer 2: h2 = relu(h1@W2+b2), K=256, N=128; wave -> cols [w*16,+16) ----
    {
        const ushort* w2f = (const ushort*)(wsb + W2F);
        f4v acc[2] = {{0,0,0,0},{0,0,0,0}};         // [mt]
        #pragma unroll
        for (int ks = 0; ks < 8; ++ks) {
            s8v a0 = *(const s8v*)&bufB[((0 * 8 + ks) * 64 + lane) * 8];
            s8v a1 = *(const s8v*)&bufB[((1 * 8 + ks) * 64 + lane) * 8];
            s8v b  = *(const s8v*)&w2f[((wid * 8 + ks) * 64 + lane) * 8];
            acc[0] = MFMA(a0, b, acc[0]);
            acc[1] = MFMA(a1, b, acc[1]);
        }
        int col = wid * 16 + fr;
        float bb = b2[col];
        #pragma unroll
        for (int mt = 0; mt < 2; ++mt) {
            int base = ((mt * 4 + (col >> 5)) * 64 + ((col >> 3) & 3) * 16) * 8 + (col & 7);
            #pragma unroll
            for (int q = 0; q < 4; ++q)
                bufC[base + (fq * 4 + q) * 8] = f2bf(fmaxf(acc[mt][q] + bb, 0.0f));
        }
    }
    __syncthreads();

    // ---- mu / lv + z (z frags restaged into bufA) ----
    {
        const ushort* wmf = (const ushort*)(wsb + WMUF);
        const ushort* wlf = (const ushort*)(wsb + WLVF);
        f4v am[2] = {{0,0,0,0},{0,0,0,0}}, al[2] = {{0,0,0,0},{0,0,0,0}};
        #pragma unroll
        for (int ks = 0; ks < 4; ++ks) {
            s8v a0 = *(const s8v*)&bufC[((0 * 4 + ks) * 64 + lane) * 8];
            s8v a1 = *(const s8v*)&bufC[((1 * 4 + ks) * 64 + lane) * 8];
            int fi = ((wid * 4 + ks) * 64 + lane) * 8;
            s8v bm = *(const s8v*)&wmf[fi];
            s8v bl = *(const s8v*)&wlf[fi];
            am[0] = MFMA(a0, bm, am[0]);
            am[1] = MFMA(a1, bm, am[1]);
            al[0] = MFMA(a0, bl, al[0]);
            al[1] = MFMA(a1, bl, al[1]);
        }
        int col = wid * 16 + fr;
        float bm = bmu[col], bl = blv[col];
        #pragma unroll
        for (int mt = 0; mt < 2; ++mt) {
            int base = ((mt * 4 + (col >> 5)) * 64 + ((col >> 3) & 3) * 16) * 8 + (col & 7);
            #pragma unroll
            for (int q = 0; q < 4; ++q) {
                int grow = row0 + mt * 16 + fq * 4 + q;
                float mu = am[mt][q] + bm;
                float lv = al[mt][q] + bl;
                out[OUT_MU + grow * DIM + col] = mu;
                out[OUT_LV + grow * DIM + col] = lv;
                float z = fmaf(epr[mt][q], __expf(0.5f * lv), mu);
                bufA[base + (fq * 4 + q) * 8] = f2bf(z);   // z frags into bufA
            }
        }
    }
    __syncthreads();

    // ---- decoder: s = z@ahat ; t = P(s) ; xhat = t@ahat + bg2 ----
    const ushort* ahf = (const ushort*)(wsb + AHF);
    const float* cf = (const float*)(wsb + COEF);
    const float a1 = cf[0], a3 = cf[1], a5 = cf[2], ssafe = cf[3];
    const int acol = wid * 16 + fr;

    s8v bfr[4];                                     // ahat n-tile wid, reused 2x
    #pragma unroll
    for (int ks = 0; ks < 4; ++ks)
        bfr[ks] = *(const s8v*)&ahf[((wid * 4 + ks) * 64 + lane) * 8];

    f4v sa[2] = {{0,0,0,0},{0,0,0,0}};
    #pragma unroll
    for (int ks = 0; ks < 4; ++ks) {
        s8v a0 = *(const s8v*)&bufA[((0 * 4 + ks) * 64 + lane) * 8];
        s8v a1 = *(const s8v*)&bufA[((1 * 4 + ks) * 64 + lane) * 8];
        sa[0] = MFMA(a0, bfr[ks], sa[0]);
        sa[1] = MFMA(a1, bfr[ks], sa[1]);
    }
    __syncthreads();                 // bufB reads (layer 2) long done; reuse for t

    {
        #pragma unroll
        for (int mt = 0; mt < 2; ++mt) {
            int base = ((mt * 4 + (acol >> 5)) * 64 + ((acol >> 3) & 3) * 16) * 8 + (acol & 7);
            #pragma unroll
            for (int q = 0; q < 4; ++q) {
                float s = sa[mt][q];
                float tv;
                if (fabsf(s) < ssafe) {             // poly path (always, in practice)
                    float s2 = s * s;
                    tv = s * fmaf(s2, fmaf(s2, a5, a3), a1);
                } else {                            // exact fallback
                    tv = 0.0f;
                    for (int c = 0; c < 32; ++c)
                        tv = fmaf(vls[64 + c], tanhf(fmaf(s, vls[c], vls[32 + c])), tv);
                }
                bufB[base + (fq * 4 + q) * 8] = f2bf(tv);
            }
        }
    }
    __syncthreads();

    f4v xa[2] = {{0,0,0,0},{0,0,0,0}};
    #pragma unroll
    for (int ks = 0; ks < 4; ++ks) {
        s8v a0 = *(const s8v*)&bufB[((0 * 4 + ks) * 64 + lane) * 8];
        s8v a1 = *(const s8v*)&bufB[((1 * 4 + ks) * 64 + lane) * 8];
        xa[0] = MFMA(a0, bfr[ks], xa[0]);
        xa[1] = MFMA(a1, bfr[ks], xa[1]);
    }
    const float bg2v = bg2p[0];
    #pragma unroll
    for (int mt = 0; mt < 2; ++mt)
        #pragma unroll
        for (int q = 0; q < 4; ++q)
            out[OUT_XHAT + (size_t)(row0 + mt * 16 + fq * 4 + q) * DIM + acol] =
                xa[mt][q] + bg2v;
}

// ---------------------------------------------------------------------------
extern "C" void kernel_launch(void* const* d_in, const int* in_sizes, int n_in,
                              void* d_out, int out_size, void* d_ws, size_t ws_size,
                              hipStream_t stream)
{
    const float* x      = (const float*)d_in[0];
    const float* eps    = (const float*)d_in[1];
    const float* W1     = (const float*)d_in[2];
    const float* b1     = (const float*)d_in[3];
    const float* W2     = (const float*)d_in[4];
    const float* b2     = (const float*)d_in[5];
    const float* Wmu    = (const float*)d_in[6];
    const float* bmu    = (const float*)d_in[7];
    const float* Wlv    = (const float*)d_in[8];
    const float* blv    = (const float*)d_in[9];
    const float* logits = (const float*)d_in[10];
    const float* Wf     = (const float*)d_in[11];
    const float* Wg1    = (const float*)d_in[12];
    const float* bg1    = (const float*)d_in[13];
    const float* Wg2    = (const float*)d_in[14];
    const float* bg2    = (const float*)d_in[15];
    const int*   itp    = (const int*)d_in[16];
    float* out = (float*)d_out;
    char* wsb  = (char*)d_ws;

    hipLaunchKernelGGL(prep_kernel, dim3(25), dim3(512), 0, stream,
                       W1, W2, Wmu, Wlv, logits, Wf, Wg1, bg1, Wg2, itp, out, wsb);
    hipLaunchKernelGGL(fused_kernel, dim3(BATCH / BRF), dim3(512), 0, stream,
                       x, eps, b1, b2, bmu, blv, bg2, out, wsb);
}

// Round 15
// 24.315 us; speedup vs baseline: 2.0586x; 1.1408x over previous
//
#include <hip/hip_runtime.h>
#include <math.h>

#define BATCH 8192
#define DIM   128
#define E1    256
#define E2    128
#define BRF   16     // fused: batch rows per block; grid 512, (512,4) -> 16 waves/CU

// output float offsets (x_hat, adj, mu, lv concatenated)
#define OUT_XHAT 0
#define OUT_ADJ  (BATCH*DIM)                 // 1048576
#define OUT_MU   (OUT_ADJ + DIM*DIM)         // 1064960
#define OUT_LV   (OUT_MU + BATCH*DIM)        // 2113536

// workspace BYTE offsets (frag-linear bf16 weight images + small f32 blocks)
#define W1F   0u          // 32768 bf16 = 65536 B
#define W2F   65536u      // 32768 bf16
#define WMUF  131072u     // 16384 bf16 = 32768 B
#define WLVF  163840u     // 16384 bf16
#define AHF   196608u     // 16384 bf16
#define COEF  229376u     // f32[8]: a1,a3,a5,s_safe
#define VBUF  229408u     // f32[96]: v[32], bg1[32], w2[32]

typedef __attribute__((ext_vector_type(8))) short s8v;   // 8 bf16 (4 VGPR)
typedef __attribute__((ext_vector_type(4))) float f4v;   // MFMA accumulator
#define MFMA(a, b, c) __builtin_amdgcn_mfma_f32_16x16x32_bf16(a, b, c, 0, 0, 0)

__device__ __forceinline__ ushort f2bf(float f) {        // RNE f32 -> bf16
    uint u = __float_as_uint(f);
    u += 0x7fffu + ((u >> 16) & 1u);
    return (ushort)(u >> 16);
}

// fast sigmoid + self-loop + threshold; single source for adj/degrees/ahat.
__device__ __forceinline__ float sigm_fast(float l, int i, int j, int it) {
    float gv = 1.0f / (1.0f + __expf(-l));
    if (i == j) gv = 1.0f;
    if (it > 50 && gv < 0.1f) gv = 0.0f;
    return gv;
}

// ---------------------------------------------------------------------------
// Kernel 1 (prep): blocks 0-23 convert weights f32 -> fragment-linear bf16.
// Block 24: adjacency, a_hat frags, tanh-poly coefficients (fast __expf).
// Fragment-linear layout for a K x N matrix: frag (nt, ks) holds the 16x32
// tile cols [nt*16,+16) x rows [ks*32,+32); elem ((nt*nKs+ks)*64 + l)*8 + j
// stores W[ks*32 + (l>>4)*8 + j][nt*16 + (l&15)].
// ---------------------------------------------------------------------------
__global__ __launch_bounds__(512) void prep_kernel(
    const float* __restrict__ W1,  const float* __restrict__ W2,
    const float* __restrict__ Wmu, const float* __restrict__ Wlv,
    const float* __restrict__ logits, const float* __restrict__ Wf,
    const float* __restrict__ Wg1, const float* __restrict__ bg1,
    const float* __restrict__ Wg2, const int* __restrict__ itp,
    float* __restrict__ out, char* __restrict__ wsb)
{
    __shared__ float gsm[16384];
    __shared__ float aux[768];
    __shared__ float vsh[32];
    const int t = threadIdx.x;

    if (blockIdx.x < 24) {
        const int tid = (int)blockIdx.x * 512 + t;       // 0..12287
        const float* W; ushort* dst; int e, N_, ksLog;
        if (tid < 4096)       { W = W1;  dst = (ushort*)(wsb + W1F);  e = tid * 8;           N_ = 256; ksLog = 2; }
        else if (tid < 8192)  { W = W2;  dst = (ushort*)(wsb + W2F);  e = (tid - 4096) * 8;  N_ = 128; ksLog = 3; }
        else if (tid < 10240) { W = Wmu; dst = (ushort*)(wsb + WMUF); e = (tid - 8192) * 8;  N_ = 128; ksLog = 2; }
        else                  { W = Wlv; dst = (ushort*)(wsb + WLVF); e = (tid - 10240) * 8; N_ = 128; ksLog = 2; }
        const int frag = e >> 9, l = (e >> 3) & 63;
        const int nt = frag >> ksLog, ks = frag & ((1 << ksLog) - 1);
        const int k0 = ks * 32 + ((l >> 4) << 3);
        const int n  = (nt << 4) + (l & 15);
        uint pk[4];
        #pragma unroll
        for (int jj = 0; jj < 4; ++jj) {
            ushort lo = f2bf(W[(k0 + 2 * jj) * N_ + n]);
            ushort hi = f2bf(W[(k0 + 2 * jj + 1) * N_ + n]);
            pk[jj] = (uint)lo | ((uint)hi << 16);
        }
        *(uint4*)(dst + e) = make_uint4(pk[0], pk[1], pk[2], pk[3]);
        return;
    }

    // ---------------- graph block (fast sigmoid throughout) ----------------
    const int it = itp[0];
    {
        const int j = t & 127, rq = t >> 7;
        float dp = 0.0f;
        #pragma unroll 4
        for (int i = rq * 32; i < rq * 32 + 32; ++i) {
            float gv = sigm_fast(logits[i * DIM + j], i, j, it);
            gsm[i * DIM + j] = gv;
            if (gv > 0.0f) dp += 1.0f;
        }
        aux[rq * 128 + j] = dp;                    // partial col sums (d_in)
    }
    __syncthreads();
    if (t < 128) {
        float d = aux[t] + aux[128 + t] + aux[256 + t] + aux[384 + t];
        aux[512 + t] = 1.0f / sqrtf(fmaxf(d, 1.0f));      // rin[j]
    }
    __syncthreads();
    {
        const int i = t & 127, cq = t >> 7;
        float dp = 0.0f;
        #pragma unroll 4
        for (int c = cq * 32; c < cq * 32 + 32; ++c)
            if (gsm[i * DIM + c] > 0.0f) dp += 1.0f;
        aux[cq * 128 + i] = dp;                    // partial row sums (d_out)
    }
    __syncthreads();
    if (t < 128) {
        float d = aux[t] + aux[128 + t] + aux[256 + t] + aux[384 + t];
        aux[640 + t] = 1.0f / sqrtf(fmaxf(d, 1.0f));      // rdout[i]
    }
    __syncthreads();
    #pragma unroll 4
    for (int p = 0; p < 32; ++p) {                 // adj out + ahat in place
        int idx = t + 512 * p;
        int i = idx >> 7, j = idx & 127;
        float gv = gsm[idx];
        out[OUT_ADJ + idx] = gv;
        gsm[idx] = gv * aux[640 + i] * aux[512 + j];
    }
    if (t < 32) {                                  // v = W_feat @ W_g1
        float acc = 0.0f;
        for (int k = 0; k < 64; ++k) acc = fmaf(Wf[k], Wg1[k * 32 + t], acc);
        vsh[t] = acc;
        float* vb = (float*)(wsb + VBUF);
        vb[t] = acc; vb[32 + t] = bg1[t]; vb[64 + t] = Wg2[t];
    }
    __syncthreads();
    {                                              // ahat fragments (K=N=128)
        ushort* ahf = (ushort*)(wsb + AHF);
        #pragma unroll
        for (int c = 0; c < 4; ++c) {
            int e = (t + c * 512) * 8;
            int frag = e >> 9, l = (e >> 3) & 63;
            int nt = frag >> 2, ks = frag & 3;
            int k0 = ks * 32 + ((l >> 4) << 3);
            int n  = (nt << 4) + (l & 15);
            uint pk[4];
            #pragma unroll
            for (int jj = 0; jj < 4; ++jj) {
                ushort lo = f2bf(gsm[(k0 + 2 * jj) * DIM + n]);
                ushort hi = f2bf(gsm[(k0 + 2 * jj + 1) * DIM + n]);
                pk[jj] = (uint)lo | ((uint)hi << 16);
            }
            *(uint4*)(ahf + e) = make_uint4(pk[0], pk[1], pk[2], pk[3]);
        }
    }
    if (t == 0) {                                  // tanh poly coefficients
        float a1 = 0, a3 = 0, a5 = 0, vmax = 0, bmax = 0;
        for (int c = 0; c < 32; ++c) {
            float v = vsh[c], w = Wg2[c], v2 = v * v;
            a1 += w * v;
            a3 -= w * v * v2 * (1.0f / 3.0f);
            a5 += w * v * v2 * v2 * (2.0f / 15.0f);
            vmax = fmaxf(vmax, fabsf(v));
            bmax = fmaxf(bmax, fabsf(bg1[c]));
        }
        float* cf = (float*)(wsb + COEF);
        cf[0] = a1; cf[1] = a3; cf[2] = a5;
        cf[3] = (bmax == 0.0f) ? 0.2f / fmaxf(vmax, 1e-30f) : -1.0f;
    }
}

// ---------------------------------------------------------------------------
// Kernel 2 (fused): round-12 best config (16 rows/block, 512 thr, grid 512,
// 16 waves/CU) + redundant mid-L1 barrier removed (7->6) + biases prefetched
// into registers at entry.
// ---------------------------------------------------------------------------
__global__ __launch_bounds__(512, 4) void fused_kernel(
    const float* __restrict__ x,   const float* __restrict__ eps,
    const float* __restrict__ b1,  const float* __restrict__ b2,
    const float* __restrict__ bmu, const float* __restrict__ blv,
    const float* __restrict__ bg2p,
    float* __restrict__ out, char* __restrict__ wsb)
{
    __shared__ __attribute__((aligned(16))) ushort bufA[2048]; // x frags, then z frags
    __shared__ __attribute__((aligned(16))) ushort bufB[4096]; // h1 frags, then t frags
    __shared__ __attribute__((aligned(16))) ushort bufC[2048]; // h2 frags
    __shared__ float vls[96];

    const int t = threadIdx.x;
    const int lane = t & 63, wid = t >> 6;          // 8 waves
    const int fr = lane & 15, fq = lane >> 4;       // C/D: col=fr, rows=fq*4+q
    const int row0 = (int)blockIdx.x * BRF;
    const int colw = wid * 16 + fr;                 // this thread's N=128 column

    // ---- prefetch eps + ALL biases into registers (hide under staging) ----
    float epr[4];
    {
        const float* eb = eps + (size_t)(row0 + fq * 4) * DIM + colw;
        #pragma unroll
        for (int q = 0; q < 4; ++q) epr[q] = eb[q * DIM];
    }
    const float br1a = b1[2 * wid * 16 + fr];       // L1 col n=0
    const float br1b = b1[(2 * wid + 1) * 16 + fr]; // L1 col n=1
    const float br2  = b2[colw];
    const float brm  = bmu[colw];
    const float brl  = blv[colw];
    const float bg2v = bg2p[0];

    if (t < 96) vls[t] = ((const float*)(wsb + VBUF))[t];

    // ---- stage x tile (16 rows) -> bf16 A-fragments; 4 floats/thread ----
    {
        const int r = t & 15, c16 = t >> 4;          // c16: 4-float column group
        const int k0 = c16 * 4;
        const int ks = k0 >> 5, g = (k0 & 31) >> 3, h = (k0 >> 2) & 1;
        float4 u = *(const float4*)(x + (size_t)(row0 + r) * DIM + k0);
        uint p0 = (uint)f2bf(u.x) | ((uint)f2bf(u.y) << 16);
        uint p1 = (uint)f2bf(u.z) | ((uint)f2bf(u.w) << 16);
        *(uint2*)&bufA[(ks * 64 + g * 16 + r) * 8 + h * 4] = make_uint2(p0, p1);
    }

    // ---- prefetch ALL layer-1 B fragments before the barrier (32 VGPR) ----
    const ushort* w1f = (const ushort*)(wsb + W1F);
    s8v w1r[2][4];
    #pragma unroll
    for (int n = 0; n < 2; ++n)
        #pragma unroll
        for (int ks = 0; ks < 4; ++ks)
            w1r[n][ks] = *(const s8v*)&w1f[(((2 * wid + n) * 4 + ks) * 64 + lane) * 8];
    __syncthreads();

    // ---- layer 1: h1 = relu(x@W1+b1), N=256; wave w -> cols [w*32,+32) ----
    // NOTE: no barrier between MFMAs and bufB write -- bufB has no prior
    // contents; bufA's z-overwrite is ordered by the end-L1 + end-L2 barriers.
    {
        f4v acc[2] = {{0,0,0,0},{0,0,0,0}};
        #pragma unroll
        for (int ks = 0; ks < 4; ++ks) {
            s8v a = *(const s8v*)&bufA[(ks * 64 + lane) * 8];
            #pragma unroll
            for (int n = 0; n < 2; ++n)
                acc[n] = MFMA(a, w1r[n][ks], acc[n]);
        }
        #pragma unroll
        for (int n = 0; n < 2; ++n) {
            int col = (2 * wid + n) * 16 + fr;       // k-index for layer 2
            float bb = n ? br1b : br1a;
            int base = (col >> 5) * 512 + (((col >> 3) & 3) * 16) * 8 + (col & 7);
            #pragma unroll
            for (int q = 0; q < 4; ++q)
                bufB[base + (fq * 4 + q) * 8] = f2bf(fmaxf(acc[n][q] + bb, 0.0f));
        }
    }
    __syncthreads();

    // ---- layer 2: h2 = relu(h1@W2+b2), K=256, N=128; wave -> cols [w*16,+16) ----
    {
        const ushort* w2f = (const ushort*)(wsb + W2F);
        f4v acc = {0, 0, 0, 0};
        #pragma unroll
        for (int ks = 0; ks < 8; ++ks) {
            s8v a = *(const s8v*)&bufB[(ks * 64 + lane) * 8];
            s8v b = *(const s8v*)&w2f[((wid * 8 + ks) * 64 + lane) * 8];
            acc = MFMA(a, b, acc);
        }
        int base = (colw >> 5) * 512 + (((colw >> 3) & 3) * 16) * 8 + (colw & 7);
        #pragma unroll
        for (int q = 0; q < 4; ++q)
            bufC[base + (fq * 4 + q) * 8] = f2bf(fmaxf(acc[q] + br2, 0.0f));
    }
    __syncthreads();

    // ---- mu / lv + z (z frags restaged into bufA) ----
    {
        const ushort* wmf = (const ushort*)(wsb + WMUF);
        const ushort* wlf = (const ushort*)(wsb + WLVF);
        f4v am = {0, 0, 0, 0}, al = {0, 0, 0, 0};
        #pragma unroll
        for (int ks = 0; ks < 4; ++ks) {
            s8v a = *(const s8v*)&bufC[(ks * 64 + lane) * 8];
            int fi = ((wid * 4 + ks) * 64 + lane) * 8;
            s8v bm = *(const s8v*)&wmf[fi];
            s8v bl = *(const s8v*)&wlf[fi];
            am = MFMA(a, bm, am);
            al = MFMA(a, bl, al);
        }
        int base = (colw >> 5) * 512 + (((colw >> 3) & 3) * 16) * 8 + (colw & 7);
        #pragma unroll
        for (int q = 0; q < 4; ++q) {
            int grow = row0 + fq * 4 + q;
            float mu = am[q] + brm;
            float lv = al[q] + brl;
            out[OUT_MU + grow * DIM + colw] = mu;
            out[OUT_LV + grow * DIM + colw] = lv;
            float z = fmaf(epr[q], __expf(0.5f * lv), mu);
            bufA[base + (fq * 4 + q) * 8] = f2bf(z);   // z frags into bufA
        }
    }
    __syncthreads();

    // ---- decoder: s = z@ahat ; t = P(s) ; xhat = t@ahat + bg2 ----
    const ushort* ahf = (const ushort*)(wsb + AHF);
    const float* cf = (const float*)(wsb + COEF);
    const float a1 = cf[0], a3 = cf[1], a5 = cf[2], ssafe = cf[3];

    s8v bfr[4];                                     // ahat n-tile wid (16 VGPR)
    #pragma unroll
    for (int ks = 0; ks < 4; ++ks)
        bfr[ks] = *(const s8v*)&ahf[((wid * 4 + ks) * 64 + lane) * 8];

    f4v sa = {0, 0, 0, 0};
    #pragma unroll
    for (int ks = 0; ks < 4; ++ks) {
        s8v a = *(const s8v*)&bufA[(ks * 64 + lane) * 8];
        sa = MFMA(a, bfr[ks], sa);
    }
    __syncthreads();                 // bufB free (layer-2 reads long done)

    {
        int base = (colw >> 5) * 512 + (((colw >> 3) & 3) * 16) * 8 + (colw & 7);
        #pragma unroll
        for (int q = 0; q < 4; ++q) {
            float s = sa[q];
            float tv;
            if (fabsf(s) < ssafe) {                 // poly path (always, in practice)
                float s2 = s * s;
                tv = s * fmaf(s2, fmaf(s2, a5, a3), a1);
            } else {                                // exact fallback
                tv = 0.0f;
                for (int c = 0; c < 32; ++c)
                    tv = fmaf(vls[64 + c], tanhf(fmaf(s, vls[c], vls[32 + c])), tv);
            }
            bufB[base + (fq * 4 + q) * 8] = f2bf(tv);
        }
    }
    __syncthreads();

    f4v xa = {0, 0, 0, 0};
    #pragma unroll
    for (int ks = 0; ks < 4; ++ks) {
        s8v a = *(const s8v*)&bufB[(ks * 64 + lane) * 8];
        xa = MFMA(a, bfr[ks], xa);
    }
    #pragma unroll
    for (int q = 0; q < 4; ++q)
        out[OUT_XHAT + (size_t)(row0 + fq * 4 + q) * DIM + colw] = xa[q] + bg2v;
}

// ---------------------------------------------------------------------------
extern "C" void kernel_launch(void* const* d_in, const int* in_sizes, int n_in,
                              void* d_out, int out_size, void* d_ws, size_t ws_size,
                              hipStream_t stream)
{
    const float* x      = (const float*)d_in[0];
    const float* eps    = (const float*)d_in[1];
    const float* W1     = (const float*)d_in[2];
    const float* b1     = (const float*)d_in[3];
    const float* W2     = (const float*)d_in[4];
    const float* b2     = (const float*)d_in[5];
    const float* Wmu    = (const float*)d_in[6];
    const float* bmu    = (const float*)d_in[7];
    const float* Wlv    = (const float*)d_in[8];
    const float* blv    = (const float*)d_in[9];
    const float* logits = (const float*)d_in[10];
    const float* Wf     = (const float*)d_in[11];
    const float* Wg1    = (const float*)d_in[12];
    const float* bg1    = (const float*)d_in[13];
    const float* Wg2    = (const float*)d_in[14];
    const float* bg2    = (const float*)d_in[15];
    const int*   itp    = (const int*)d_in[16];
    float* out = (float*)d_out;
    char* wsb  = (char*)d_ws;

    hipLaunchKernelGGL(prep_kernel, dim3(25), dim3(512), 0, stream,
                       W1, W2, Wmu, Wlv, logits, Wf, Wg1, bg1, Wg2, itp, out, wsb);
    hipLaunchKernelGGL(fused_kernel, dim3(BATCH / BRF), dim3(512), 0, stream,
                       x, eps, b1, b2, bmu, blv, bg2, out, wsb);
}